// Round 9
// baseline (94.106 us; speedup 1.0000x reference)
//
#include <hip/hip_runtime.h>
#include <stdint.h>
#include <math.h>

#define N_PTS 8192
#define WPB   8
#define TPB   (WPB * 64)
#define NBLK  (N_PTS / WPB)        // 1024 blocks for main
#define GRIDC 64                   // 64x64 cells
#define NCELL (GRIDC * GRIDC)
#define CW    (9.0f / 64.0f)       // cell width over [-4.5, 4.5]
#define CINV  (64.0f / 9.0f)

typedef __fp16 h2 __attribute__((ext_vector_type(2)));
typedef uint32_t u32;

__device__ __forceinline__ u32 pksub(u32 a, u32 b) {
  u32 d;
  asm("v_pk_add_f16 %0, %1, %2 neg_lo:[0,1] neg_hi:[0,1]" : "=v"(d) : "v"(a), "v"(b));
  return d;
}
__device__ __forceinline__ float dot2u(u32 a, u32 b, float c) {
#if __has_builtin(__builtin_amdgcn_fdot2)
  return __builtin_amdgcn_fdot2(__builtin_bit_cast(h2, a), __builtin_bit_cast(h2, b), c, false);
#else
  h2 x = __builtin_bit_cast(h2, a), y = __builtin_bit_cast(h2, b);
  return fmaf((float)x.x, (float)y.x, fmaf((float)x.y, (float)y.y, c));
#endif
}
__device__ __forceinline__ u32 cvtpk(float a, float b) {
  return __builtin_bit_cast(u32, __builtin_amdgcn_cvt_pkrtz(a, b));
}
__device__ __forceinline__ int cellc(float v) {
  int c = (int)floorf((v + 4.5f) * CINV);
  return c < 0 ? 0 : (c > GRIDC - 1 ? GRIDC - 1 : c);
}

// ---------------- threefry2x32 (JAX partitionable random_bits) ----------------
__device__ __forceinline__ uint32_t rotl32(uint32_t x, int r) {
  return (x << r) | (x >> (32 - r));
}
__device__ __forceinline__ uint32_t threefry_bits(uint32_t idx) {
  const uint32_t k0 = 0u, k1 = 42u;
  const uint32_t k2c = k0 ^ k1 ^ 0x1BD11BDAu;
  uint32_t x0 = 0u, x1 = idx;
  x0 += k0; x1 += k1;
  x0 += x1; x1 = rotl32(x1, 13); x1 ^= x0;
  x0 += x1; x1 = rotl32(x1, 15); x1 ^= x0;
  x0 += x1; x1 = rotl32(x1, 26); x1 ^= x0;
  x0 += x1; x1 = rotl32(x1,  6); x1 ^= x0;
  x0 += k1; x1 += k2c + 1u;
  x0 += x1; x1 = rotl32(x1, 17); x1 ^= x0;
  x0 += x1; x1 = rotl32(x1, 29); x1 ^= x0;
  x0 += x1; x1 = rotl32(x1, 16); x1 ^= x0;
  x0 += x1; x1 = rotl32(x1, 24); x1 ^= x0;
  x0 += k2c; x1 += k0 + 2u;
  x0 += x1; x1 = rotl32(x1, 13); x1 ^= x0;
  x0 += x1; x1 = rotl32(x1, 15); x1 ^= x0;
  x0 += x1; x1 = rotl32(x1, 26); x1 ^= x0;
  x0 += x1; x1 = rotl32(x1,  6); x1 ^= x0;
  x0 += k0; x1 += k1 + 3u;
  x0 += x1; x1 = rotl32(x1, 17); x1 ^= x0;
  x0 += x1; x1 = rotl32(x1, 29); x1 ^= x0;
  x0 += x1; x1 = rotl32(x1, 16); x1 ^= x0;
  x0 += x1; x1 = rotl32(x1, 24); x1 ^= x0;
  x0 += k1; x1 += k2c + 4u;
  x0 += x1; x1 = rotl32(x1, 13); x1 ^= x0;
  x0 += x1; x1 = rotl32(x1, 15); x1 ^= x0;
  x0 += x1; x1 = rotl32(x1, 26); x1 ^= x0;
  x0 += x1; x1 = rotl32(x1,  6); x1 ^= x0;
  x0 += k2c; x1 += k0 + 5u;
  return x0 ^ x1;
}
__device__ __forceinline__ float erfinv_xla(float x) {
  float w = -log1pf(-x * x);
  float p;
  if (w < 5.0f) {
    w -= 2.5f;
    p = 2.81022636e-08f;
    p = fmaf(p, w, 3.43273939e-07f);
    p = fmaf(p, w, -3.5233877e-06f);
    p = fmaf(p, w, -4.39150654e-06f);
    p = fmaf(p, w, 0.00021858087f);
    p = fmaf(p, w, -0.00125372503f);
    p = fmaf(p, w, -0.00417768164f);
    p = fmaf(p, w, 0.246640727f);
    p = fmaf(p, w, 1.50140941f);
  } else {
    w = sqrtf(w) - 3.0f;
    p = -0.000200214257f;
    p = fmaf(p, w, 0.000100950558f);
    p = fmaf(p, w, 0.00134934322f);
    p = fmaf(p, w, -0.00367342844f);
    p = fmaf(p, w, 0.00573950773f);
    p = fmaf(p, w, -0.0076224613f);
    p = fmaf(p, w, 0.00943887047f);
    p = fmaf(p, w, 1.00167406f);
    p = fmaf(p, w, 2.83297682f);
  }
  return p * x;
}
__device__ __forceinline__ float jax_noise(uint32_t idx) {
  uint32_t bits = threefry_bits(idx);
  float uf = __uint_as_float((bits >> 9) | 0x3F800000u) - 1.0f;
  const float lo_u = -0.99999994f;
  float u = fmaxf(lo_u, fmaf(uf, 2.0f, lo_u));
  return 1.4142135623730951f * erfinv_xla(u) * 0.01f;
}

// ---------------- K1: per-cell counts ----------------
__global__ __launch_bounds__(256) void count_kernel(const float* __restrict__ x,
                                                    u32* __restrict__ counts) {
  int i = blockIdx.x * 256 + threadIdx.x;
  float2 p = ((const float2*)x)[i];
  int cell = cellc(p.y) * GRIDC + cellc(p.x);
  atomicAdd(&counts[cell], 1u);
}

// ---------------- K2: prefix sum + cursor init + stats ----------------
__global__ __launch_bounds__(1024) void prefix_stats_kernel(const float* __restrict__ x,
                                                            u32* __restrict__ counts,  // -> cursor
                                                            u32* __restrict__ base,
                                                            float* __restrict__ stats) {
  __shared__ u32 ssc[1024];
  __shared__ double sd[1024][4];
  const int t = threadIdx.x;
  u32 c[4]; u32 sum = 0;
#pragma unroll
  for (int k = 0; k < 4; ++k) { c[k] = counts[t * 4 + k]; sum += c[k]; }
  ssc[t] = sum;
  __syncthreads();
  for (int off = 1; off < 1024; off <<= 1) {
    u32 v = (t >= off) ? ssc[t - off] : 0u;
    __syncthreads();
    ssc[t] += v;
    __syncthreads();
  }
  u32 run = ssc[t] - sum;  // exclusive
#pragma unroll
  for (int k = 0; k < 4; ++k) { base[t * 4 + k] = run; run += c[k]; }
  if (t == 1023) base[NCELL] = run;  // = 8192
  __syncthreads();
#pragma unroll
  for (int k = 0; k < 4; ++k) counts[t * 4 + k] = base[t * 4 + k];  // cursor = base

  // deterministic f64 column stats (8 points per thread)
  double s0 = 0, s1 = 0, q0 = 0, q1 = 0;
#pragma unroll
  for (int k = 0; k < 8; ++k) {
    float2 p = ((const float2*)x)[t * 8 + k];
    s0 += (double)p.x; s1 += (double)p.y;
    q0 += (double)p.x * (double)p.x; q1 += (double)p.y * (double)p.y;
  }
  sd[t][0] = s0; sd[t][1] = s1; sd[t][2] = q0; sd[t][3] = q1;
  __syncthreads();
  for (int off = 512; off > 0; off >>= 1) {
    if (t < off) {
      sd[t][0] += sd[t + off][0]; sd[t][1] += sd[t + off][1];
      sd[t][2] += sd[t + off][2]; sd[t][3] += sd[t + off][3];
    }
    __syncthreads();
  }
  if (t == 0) {
    double n = (double)N_PTS;
    double m0 = sd[0][0] / n, m1 = sd[0][1] / n;
    stats[0] = (float)m0;
    stats[1] = (float)m1;
    stats[2] = (float)sqrt((sd[0][2] - n * m0 * m0) / (n - 1.0));
    stats[3] = (float)sqrt((sd[0][3] - n * m1 * m1) / (n - 1.0));
  }
}

// ---------------- K3: placement (arbitrary within-cell order) ----------------
__global__ __launch_bounds__(256) void place_kernel(const float* __restrict__ x,
                                                    u32* __restrict__ cursor,
                                                    u32* __restrict__ tmp_pt,
                                                    u32* __restrict__ tmp_ci) {
  int i = blockIdx.x * 256 + threadIdx.x;
  float2 p = ((const float2*)x)[i];
  int cell = cellc(p.y) * GRIDC + cellc(p.x);
  u32 slot = atomicAdd(&cursor[cell], 1u);
  tmp_pt[slot] = cvtpk(p.x, p.y);
  tmp_ci[slot] = ((u32)cell << 13) | (u32)i;
}

// ---------------- K4: stable rank within cell -> deterministic sorted arrays ----------------
__global__ __launch_bounds__(256) void rank_kernel(const u32* __restrict__ base,
                                                   const u32* __restrict__ tmp_pt,
                                                   const u32* __restrict__ tmp_ci,
                                                   u32* __restrict__ spt,
                                                   unsigned short* __restrict__ sidx) {
  int s = blockIdx.x * 256 + threadIdx.x;
  u32 v = tmp_ci[s];
  u32 cell = v >> 13, i = v & 8191u;
  u32 lo = base[cell], hi = base[cell + 1];
  u32 rank = 0;
  for (u32 j = lo; j < hi; ++j) rank += ((tmp_ci[j] & 8191u) < i) ? 1u : 0u;
  u32 d = lo + rank;
  spt[d] = tmp_pt[s];
  sidx[d] = (unsigned short)i;
}

// ---------------- K5: main — windowed sigma + drift + noised h ----------------
__global__ __launch_bounds__(TPB, 8) void main_kernel(const float* __restrict__ x,
                                                      const float* __restrict__ stats,
                                                      const u32* __restrict__ base,
                                                      const u32* __restrict__ spt,
                                                      const unsigned short* __restrict__ sidx,
                                                      float* __restrict__ h_out,
                                                      double* __restrict__ partials) {
  __shared__ float hrow[WPB * 2];
  const int t = threadIdx.x;
  const int w = t >> 6;
  const int s = t & 63;
  const int p = blockIdx.x * WPB + w;      // sorted position = this wave's row
  const int orig = (int)sidx[p];
  const float2 xg = ((const float2*)x)[orig];
  const u32 xihu = cvtpk(xg.x, xg.y);
  const int cx = cellc(xg.x), cy = cellc(xg.y);
  const float INF = 3.402823466e+38f;

  // ---- phase A: expanding cell-box scan with CONTINUOUS STREAM STRIDING ----
  // lane = (stream position) mod 64, stream = concatenation of row-band ranges.
  // This keeps per-lane candidate counts uniform (band-restart concentrated
  // candidates on low lanes and overflowed the capped lists -> wrong sigma).
  float d2k;
  int r = 2;
  for (;;) {
    float r0 = INF, r1 = INF, r2 = INF, r3 = INF, r4 = INF, r5 = INF;
    const int cxl = max(cx - r, 0), cxh = min(cx + r, GRIDC - 1);
    const int cyl = max(cy - r, 0), cyh = min(cy + r, GRIDC - 1);
    u32 acc = 0;  // wave-uniform stream offset
    for (int yy = cyl; yy <= cyh; ++yy) {
      const int rowb = yy << 6;
      u32 lo = base[rowb + cxl];
      u32 len = base[rowb + cxh + 1] - lo;
      u32 k0 = ((u32)s - acc) & 63u;
      for (u32 k = k0; k < len; k += 64u) {
        u32 qp = spt[lo + k];
        u32 e = pksub(xihu, qp);
        float d2 = dot2u(e, e, 0.0f);
        // branchless sorted cap-6 insert
        r5 = fminf(fmaxf(r4, d2), r5);
        r4 = fminf(fmaxf(r3, d2), r4);
        r3 = fminf(fmaxf(r2, d2), r3);
        r2 = fminf(fmaxf(r1, d2), r2);
        r1 = fminf(fmaxf(r0, d2), r1);
        r0 = fminf(r0, d2);
      }
      acc += len;
    }
    // exact rank-32 over 64 sorted cap-6 lists: binary search in f16-bit space
    u32 b0 = (u32)__builtin_bit_cast(unsigned short, (__fp16)r0);
    u32 b1 = (u32)__builtin_bit_cast(unsigned short, (__fp16)r1);
    u32 b2 = (u32)__builtin_bit_cast(unsigned short, (__fp16)r2);
    u32 b3 = (u32)__builtin_bit_cast(unsigned short, (__fp16)r3);
    u32 b4 = (u32)__builtin_bit_cast(unsigned short, (__fp16)r4);
    u32 b5 = (u32)__builtin_bit_cast(unsigned short, (__fp16)r5);
    u32 blo = 0u, bhi = 0x7C01u;
    for (int it = 0; it < 15; ++it) {
      u32 mid = (blo + bhi) >> 1;
      int c = __popcll(__ballot(b0 < mid)) + __popcll(__ballot(b1 < mid)) +
              __popcll(__ballot(b2 < mid)) + __popcll(__ballot(b3 < mid)) +
              __popcll(__ballot(b4 < mid)) + __popcll(__ballot(b5 < mid));
      bool ge = (c >= 32);
      bhi = ge ? mid : bhi;
      blo = ge ? blo : mid;
    }
    unsigned short v32 = (unsigned short)(bhi - 1u);
    d2k = (float)__builtin_bit_cast(__fp16, v32);  // 32nd-smallest d^2 over scanned box

    // verify: true 32-NN ball (with f16 slack) inside scanned box?
    float d32 = sqrtf(d2k) + 1e-2f;
    float mxl = (cxl > 0) ? xg.x - (-4.5f + cxl * CW) : 1e9f;
    float mxh = (cxh < GRIDC - 1) ? (-4.5f + (cxh + 1) * CW) - xg.x : 1e9f;
    float myl = (cyl > 0) ? xg.y - (-4.5f + cyl * CW) : 1e9f;
    float myh = (cyh < GRIDC - 1) ? (-4.5f + (cyh + 1) * CW) - xg.y : 1e9f;
    float margin = fminf(fminf(mxl, mxh), fminf(myl, myh));
    if (d32 <= margin) break;
    r <<= 1;  // 2 -> 4 -> 8 -> 16 -> 32 -> 64 (full grid => margins 1e9 => terminates)
  }

  const float den = fmaf(2.0f, d2k, 1e-8f);
  const float nc1 = -1.4426950408889634f / den;  // w_scaled = 2^(10 + nc1*d)
  // truncation: 2^(10+nc1*d) < 2^-13  =>  d > 23/|nc1| = 15.94*den
  const float dcut = 15.943f * den;

  // ---- phase B: banded window scan (stream-strided), weight sums ----
  float sw = 0.f, swx = 0.f, swy = 0.f;
  {
    const int bxl = cellc(xg.x - dcut), bxh = cellc(xg.x + dcut);
    const int byl = cellc(xg.y - dcut), byh = cellc(xg.y + dcut);
    u32 acc = 0;
    for (int yy = byl; yy <= byh; ++yy) {
      const int rowb = yy << 6;
      u32 lo = base[rowb + bxl];
      u32 len = base[rowb + bxh + 1] - lo;
      u32 k0 = ((u32)s - acc) & 63u;
      for (u32 k = k0; k < len; k += 64u) {
        u32 qp = spt[lo + k];
        u32 e = pksub(xihu, qp);
        float d = __builtin_amdgcn_sqrtf(dot2u(e, e, 0.0f));
        float wgt = __builtin_amdgcn_exp2f(fmaf(nc1, d, 10.0f));
        h2 ph = __builtin_bit_cast(h2, qp);
        sw += wgt;
        swx = fmaf(wgt, (float)ph.x, swx);
        swy = fmaf(wgt, (float)ph.y, swy);
      }
      acc += len;
    }
  }
#pragma unroll
  for (int m = 1; m < 64; m <<= 1) {
    sw  += __shfl_xor(sw,  m);
    swx += __shfl_xor(swx, m);
    swy += __shfl_xor(swy, m);
  }

  if (s < 2) {
    const float mean = stats[s];
    float inv   = 1.0f / (sw + 1e-8f);               // 2^10 scaling cancels in drift
    float drift = (s == 0 ? swx : swy) * inv - mean; // centered drift
    float xcv   = (s == 0 ? xg.x : xg.y) - mean;     // centered own coord (f32 exact)
    uint32_t idx = 2u * (uint32_t)orig + (uint32_t)s;
    float h = fmaf(0.5f, drift - xcv, xcv) + jax_noise(idx);  // step = D^-alpha = 0.5
    h_out[idx] = h;
    hrow[w * 2 + s] = h;
  }
  __syncthreads();
  if (t < 2) {  // deterministic per-block column partials (f64)
    double sm = 0.0, sq = 0.0;
#pragma unroll
    for (int k = 0; k < WPB; ++k) {
      double v = (double)hrow[k * 2 + t];
      sm += v; sq += v * v;
    }
    partials[blockIdx.x * 4 + t]     = sm;
    partials[blockIdx.x * 4 + 2 + t] = sq;
  }
}

// ------- K6: every block reduces partials (deterministic) + scales its slice -------
__global__ __launch_bounds__(256) void scalefinal_kernel(const double* __restrict__ partials,
                                                         const float* __restrict__ stats,
                                                         float* __restrict__ h) {
  __shared__ double red[256][4];
  __shared__ float sc[2];
  const int t = threadIdx.x;
  double a0 = 0, a1 = 0, a2 = 0, a3 = 0;
#pragma unroll
  for (int kb = 0; kb < NBLK / 256; ++kb) {
    int b = kb * 256 + t;
    a0 += partials[b * 4 + 0]; a1 += partials[b * 4 + 1];
    a2 += partials[b * 4 + 2]; a3 += partials[b * 4 + 3];
  }
  red[t][0] = a0; red[t][1] = a1; red[t][2] = a2; red[t][3] = a3;
  __syncthreads();
  for (int st = 128; st > 0; st >>= 1) {
    if (t < st) {
      red[t][0] += red[t + st][0]; red[t][1] += red[t + st][1];
      red[t][2] += red[t + st][2]; red[t][3] += red[t + st][3];
    }
    __syncthreads();
  }
  if (t < 2) {
    double n = (double)N_PTS;
    double m = red[0][t] / n;
    double v = (red[0][2 + t] - n * m * m) / (n - 1.0);
    sc[t] = stats[2 + t] / ((float)sqrt(v) + 1e-8f);
  }
  __syncthreads();
  int i = blockIdx.x * 256 + t;
  int d = i & 1;
  h[i] = fmaf(h[i], sc[d], stats[d]);
}

extern "C" void kernel_launch(void* const* d_in, const int* in_sizes, int n_in,
                              void* d_out, int out_size, void* d_ws, size_t ws_size,
                              hipStream_t stream) {
  const float* x = (const float*)d_in[0];
  float* out = (float*)d_out;
  char* W = (char*)d_ws;
  float* stats = (float*)W;                                  // [0,16)
  u32* counts = (u32*)(W + 128);                             // 4096 u32
  u32* base   = (u32*)(W + 16512);                           // 4097 u32
  unsigned short* sidx = (unsigned short*)(W + 33024);       // 8192 u16
  u32* tmp_pt = (u32*)(W + 49408);                           // 8192 u32
  u32* tmp_ci = (u32*)(W + 82176);                           // 8192 u32
  u32* spt    = (u32*)(W + 114944);                          // 8192 u32
  double* partials = (double*)(W + 49408);                   // overlays tmp (dead after rank)

  hipMemsetAsync(counts, 0, NCELL * sizeof(u32), stream);
  count_kernel<<<N_PTS / 256, 256, 0, stream>>>(x, counts);
  prefix_stats_kernel<<<1, 1024, 0, stream>>>(x, counts, base, stats);
  place_kernel<<<N_PTS / 256, 256, 0, stream>>>(x, counts, tmp_pt, tmp_ci);
  rank_kernel<<<N_PTS / 256, 256, 0, stream>>>(base, tmp_pt, tmp_ci, spt, sidx);
  main_kernel<<<NBLK, TPB, 0, stream>>>(x, stats, base, spt, sidx, out, partials);
  scalefinal_kernel<<<16384 / 256, 256, 0, stream>>>(partials, stats, out);
}

// Round 10
// 84.599 us; speedup vs baseline: 1.1124x; 1.1124x over previous
//
#include <hip/hip_runtime.h>
#include <stdint.h>
#include <math.h>

#define N_PTS 8192
#define WPB   8
#define TPB   (WPB * 64)
#define NBLK  (N_PTS / WPB)        // 1024 blocks for main
#define GRIDC 64
#define NCELL (GRIDC * GRIDC)
#define CW    (9.0f / 64.0f)       // cell width over [-4.5, 4.5]
#define CINV  (64.0f / 9.0f)

typedef __fp16 h2 __attribute__((ext_vector_type(2)));
typedef uint32_t u32;

__device__ __forceinline__ u32 pksub(u32 a, u32 b) {
  u32 d;
  asm("v_pk_add_f16 %0, %1, %2 neg_lo:[0,1] neg_hi:[0,1]" : "=v"(d) : "v"(a), "v"(b));
  return d;
}
__device__ __forceinline__ float dot2u(u32 a, u32 b, float c) {
#if __has_builtin(__builtin_amdgcn_fdot2)
  return __builtin_amdgcn_fdot2(__builtin_bit_cast(h2, a), __builtin_bit_cast(h2, b), c, false);
#else
  h2 x = __builtin_bit_cast(h2, a), y = __builtin_bit_cast(h2, b);
  return fmaf((float)x.x, (float)y.x, fmaf((float)x.y, (float)y.y, c));
#endif
}
__device__ __forceinline__ u32 cvtpk(float a, float b) {
  return __builtin_bit_cast(u32, __builtin_amdgcn_cvt_pkrtz(a, b));
}
__device__ __forceinline__ int cellc(float v) {
  int c = (int)floorf((v + 4.5f) * CINV);
  return c < 0 ? 0 : (c > GRIDC - 1 ? GRIDC - 1 : c);
}

// ---------------- threefry2x32 (JAX partitionable random_bits) ----------------
__device__ __forceinline__ uint32_t rotl32(uint32_t x, int r) {
  return (x << r) | (x >> (32 - r));
}
__device__ __forceinline__ uint32_t threefry_bits(uint32_t idx) {
  const uint32_t k0 = 0u, k1 = 42u;
  const uint32_t k2c = k0 ^ k1 ^ 0x1BD11BDAu;
  uint32_t x0 = 0u, x1 = idx;
  x0 += k0; x1 += k1;
  x0 += x1; x1 = rotl32(x1, 13); x1 ^= x0;
  x0 += x1; x1 = rotl32(x1, 15); x1 ^= x0;
  x0 += x1; x1 = rotl32(x1, 26); x1 ^= x0;
  x0 += x1; x1 = rotl32(x1,  6); x1 ^= x0;
  x0 += k1; x1 += k2c + 1u;
  x0 += x1; x1 = rotl32(x1, 17); x1 ^= x0;
  x0 += x1; x1 = rotl32(x1, 29); x1 ^= x0;
  x0 += x1; x1 = rotl32(x1, 16); x1 ^= x0;
  x0 += x1; x1 = rotl32(x1, 24); x1 ^= x0;
  x0 += k2c; x1 += k0 + 2u;
  x0 += x1; x1 = rotl32(x1, 13); x1 ^= x0;
  x0 += x1; x1 = rotl32(x1, 15); x1 ^= x0;
  x0 += x1; x1 = rotl32(x1, 26); x1 ^= x0;
  x0 += x1; x1 = rotl32(x1,  6); x1 ^= x0;
  x0 += k0; x1 += k1 + 3u;
  x0 += x1; x1 = rotl32(x1, 17); x1 ^= x0;
  x0 += x1; x1 = rotl32(x1, 29); x1 ^= x0;
  x0 += x1; x1 = rotl32(x1, 16); x1 ^= x0;
  x0 += x1; x1 = rotl32(x1, 24); x1 ^= x0;
  x0 += k1; x1 += k2c + 4u;
  x0 += x1; x1 = rotl32(x1, 13); x1 ^= x0;
  x0 += x1; x1 = rotl32(x1, 15); x1 ^= x0;
  x0 += x1; x1 = rotl32(x1, 26); x1 ^= x0;
  x0 += x1; x1 = rotl32(x1,  6); x1 ^= x0;
  x0 += k2c; x1 += k0 + 5u;
  return x0 ^ x1;
}
__device__ __forceinline__ float erfinv_xla(float x) {
  float w = -log1pf(-x * x);
  float p;
  if (w < 5.0f) {
    w -= 2.5f;
    p = 2.81022636e-08f;
    p = fmaf(p, w, 3.43273939e-07f);
    p = fmaf(p, w, -3.5233877e-06f);
    p = fmaf(p, w, -4.39150654e-06f);
    p = fmaf(p, w, 0.00021858087f);
    p = fmaf(p, w, -0.00125372503f);
    p = fmaf(p, w, -0.00417768164f);
    p = fmaf(p, w, 0.246640727f);
    p = fmaf(p, w, 1.50140941f);
  } else {
    w = sqrtf(w) - 3.0f;
    p = -0.000200214257f;
    p = fmaf(p, w, 0.000100950558f);
    p = fmaf(p, w, 0.00134934322f);
    p = fmaf(p, w, -0.00367342844f);
    p = fmaf(p, w, 0.00573950773f);
    p = fmaf(p, w, -0.0076224613f);
    p = fmaf(p, w, 0.00943887047f);
    p = fmaf(p, w, 1.00167406f);
    p = fmaf(p, w, 2.83297682f);
  }
  return p * x;
}
__device__ __forceinline__ float jax_noise(uint32_t idx) {
  uint32_t bits = threefry_bits(idx);
  float uf = __uint_as_float((bits >> 9) | 0x3F800000u) - 1.0f;
  const float lo_u = -0.99999994f;
  float u = fmaxf(lo_u, fmaf(uf, 2.0f, lo_u));
  return 1.4142135623730951f * erfinv_xla(u) * 0.01f;
}

// ---------------- K1: per-cell counts + f64 stat partials ----------------
__global__ __launch_bounds__(256) void count_kernel(const float* __restrict__ x,
                                                    u32* __restrict__ counts,
                                                    double* __restrict__ statpart) {
  __shared__ double red[256][4];
  const int t = threadIdx.x;
  int i = blockIdx.x * 256 + t;
  float2 p = ((const float2*)x)[i];
  int cell = cellc(p.y) * GRIDC + cellc(p.x);
  atomicAdd(&counts[cell], 1u);
  red[t][0] = (double)p.x; red[t][1] = (double)p.y;
  red[t][2] = (double)p.x * (double)p.x; red[t][3] = (double)p.y * (double)p.y;
  __syncthreads();
  for (int st = 128; st > 0; st >>= 1) {
    if (t < st) {
      red[t][0] += red[t + st][0]; red[t][1] += red[t + st][1];
      red[t][2] += red[t + st][2]; red[t][3] += red[t + st][3];
    }
    __syncthreads();
  }
  if (t < 4) statpart[blockIdx.x * 4 + t] = red[0][t];
}

// ---------------- K2: prefix + cursor + integral image + stats finish ----------------
__global__ __launch_bounds__(1024) void prefix_kernel(u32* __restrict__ counts,  // -> cursor
                                                      u32* __restrict__ base,
                                                      u32* __restrict__ iimg,
                                                      const double* __restrict__ statpart,
                                                      float* __restrict__ stats) {
  __shared__ u32 ssc[1024];
  const int t = threadIdx.x;
  u32 c[4]; u32 sum = 0;
#pragma unroll
  for (int k = 0; k < 4; ++k) { c[k] = counts[t * 4 + k]; sum += c[k]; }
  ssc[t] = sum;
  __syncthreads();
  for (int off = 1; off < 1024; off <<= 1) {
    u32 v = (t >= off) ? ssc[t - off] : 0u;
    __syncthreads();
    ssc[t] += v;
    __syncthreads();
  }
  u32 run = ssc[t] - sum;  // exclusive
#pragma unroll
  for (int k = 0; k < 4; ++k) { base[t * 4 + k] = run; run += c[k]; }
  if (t == 1023) base[NCELL] = run;  // = 8192
  __syncthreads();
#pragma unroll
  for (int k = 0; k < 4; ++k) counts[t * 4 + k] = base[t * 4 + k];  // cursor = base

  // 2D integral image: iimg[yy*65+xx] = # points with cell_y < yy and cell_x < xx
  if (t <= 64) {
    u32 acc = 0;
    iimg[t] = 0;
    for (int yy = 0; yy < GRIDC; ++yy) {
      acc += base[yy * GRIDC + t] - base[yy * GRIDC];
      iimg[(yy + 1) * 65 + t] = acc;
    }
  }
  // stats finish
  if (t == 0) {
    double a0 = 0, a1 = 0, b0 = 0, b1 = 0;
    for (int k = 0; k < 32; ++k) {
      a0 += statpart[k * 4 + 0]; a1 += statpart[k * 4 + 1];
      b0 += statpart[k * 4 + 2]; b1 += statpart[k * 4 + 3];
    }
    double n = (double)N_PTS;
    double m0 = a0 / n, m1 = a1 / n;
    stats[0] = (float)m0;
    stats[1] = (float)m1;
    stats[2] = (float)sqrt((b0 - n * m0 * m0) / (n - 1.0));
    stats[3] = (float)sqrt((b1 - n * m1 * m1) / (n - 1.0));
  }
}

// ---------------- K3: placement ----------------
__global__ __launch_bounds__(256) void place_kernel(const float* __restrict__ x,
                                                    u32* __restrict__ cursor,
                                                    u32* __restrict__ tmp_pt,
                                                    u32* __restrict__ tmp_ci) {
  int i = blockIdx.x * 256 + threadIdx.x;
  float2 p = ((const float2*)x)[i];
  int cell = cellc(p.y) * GRIDC + cellc(p.x);
  u32 slot = atomicAdd(&cursor[cell], 1u);
  tmp_pt[slot] = cvtpk(p.x, p.y);
  tmp_ci[slot] = ((u32)cell << 13) | (u32)i;
}

// ---------------- K4: stable rank within cell ----------------
__global__ __launch_bounds__(256) void rank_kernel(const u32* __restrict__ base,
                                                   const u32* __restrict__ tmp_pt,
                                                   const u32* __restrict__ tmp_ci,
                                                   u32* __restrict__ spt,
                                                   unsigned short* __restrict__ sidx) {
  int s = blockIdx.x * 256 + threadIdx.x;
  u32 v = tmp_ci[s];
  u32 cell = v >> 13, i = v & 8191u;
  u32 lo = base[cell], hi = base[cell + 1];
  u32 rank = 0;
  for (u32 j = lo; j < hi; ++j) rank += ((tmp_ci[j] & 8191u) < i) ? 1u : 0u;
  u32 d = lo + rank;
  spt[d] = tmp_pt[s];
  sidx[d] = (unsigned short)i;
}

// ---------------- K5: main ----------------
__global__ __launch_bounds__(TPB, 8) void main_kernel(const float* __restrict__ x,
                                                      const float* __restrict__ stats,
                                                      const u32* __restrict__ base,
                                                      const u32* __restrict__ iimg,
                                                      const u32* __restrict__ spt,
                                                      const unsigned short* __restrict__ sidx,
                                                      float* __restrict__ h_out,
                                                      double* __restrict__ partials) {
  __shared__ float hrow[WPB * 2];
  const int t = threadIdx.x;
  const int w = t >> 6;
  const int s = t & 63;
  const int p = blockIdx.x * WPB + w;
  const int orig = (int)sidx[p];
  const float2 xg = ((const float2*)x)[orig];
  const u32 xihu = cvtpk(xg.x, xg.y);
  const int cx = cellc(xg.x), cy = cellc(xg.y);
  const float INF = 3.402823466e+38f;

  // ---- pre-size r from integral image (4 scalar loads per step) ----
  int r = 1;
  bool fullA = false;
  for (;;) {
    int cxl = max(cx - r, 0), cxh = min(cx + r, GRIDC - 1);
    int cyl = max(cy - r, 0), cyh = min(cy + r, GRIDC - 1);
    u32 cnt = iimg[(cyh + 1) * 65 + cxh + 1] - iimg[cyl * 65 + cxh + 1]
            - iimg[(cyh + 1) * 65 + cxl] + iimg[cyl * 65 + cxl];
    if (cnt >= 100u) break;
    if (r >= 8) { fullA = true; break; }
    r = (3 * r + 1) >> 1;  // 1,2,3,5,8
  }

  // ---- phase A: scan (windowed w/ stream striding, or full contiguous), verify ----
  float d2k;
  for (;;) {
    float r0 = INF, r1 = INF, r2 = INF, r3 = INF, r4 = INF, r5 = INF;
    int cxl, cxh, cyl, cyh;
    if (fullA) { cxl = 0; cxh = GRIDC - 1; cyl = 0; cyh = GRIDC - 1; }
    else {
      cxl = max(cx - r, 0); cxh = min(cx + r, GRIDC - 1);
      cyl = max(cy - r, 0); cyh = min(cy + r, GRIDC - 1);
    }
#define INS6(d2)                      \
    r5 = fminf(fmaxf(r4, d2), r5);    \
    r4 = fminf(fmaxf(r3, d2), r4);    \
    r3 = fminf(fmaxf(r2, d2), r3);    \
    r2 = fminf(fmaxf(r1, d2), r2);    \
    r1 = fminf(fmaxf(r0, d2), r1);    \
    r0 = fminf(r0, d2);
    if (fullA) {
      for (u32 j = (u32)s; j < N_PTS; j += 64u) {
        u32 qp = spt[j];
        u32 e = pksub(xihu, qp);
        float d2 = dot2u(e, e, 0.0f);
        INS6(d2);
      }
    } else {
      u32 acc = 0;  // continuous stream striding across bands
      for (int yy = cyl; yy <= cyh; ++yy) {
        const int rowb = yy << 6;
        u32 lo = base[rowb + cxl];
        u32 len = base[rowb + cxh + 1] - lo;
        u32 k0 = ((u32)s - acc) & 63u;
        for (u32 k = k0; k < len; k += 64u) {
          u32 qp = spt[lo + k];
          u32 e = pksub(xihu, qp);
          float d2 = dot2u(e, e, 0.0f);
          INS6(d2);
        }
        acc += len;
      }
    }
#undef INS6
    // exact rank-32 over 64 sorted cap-6 lists (f16-bit binary search)
    u32 b0 = (u32)__builtin_bit_cast(unsigned short, (__fp16)r0);
    u32 b1 = (u32)__builtin_bit_cast(unsigned short, (__fp16)r1);
    u32 b2 = (u32)__builtin_bit_cast(unsigned short, (__fp16)r2);
    u32 b3 = (u32)__builtin_bit_cast(unsigned short, (__fp16)r3);
    u32 b4 = (u32)__builtin_bit_cast(unsigned short, (__fp16)r4);
    u32 b5 = (u32)__builtin_bit_cast(unsigned short, (__fp16)r5);
    u32 blo = 0u, bhi = 0x7C01u;
    for (int it = 0; it < 15; ++it) {
      u32 mid = (blo + bhi) >> 1;
      int c = __popcll(__ballot(b0 < mid)) + __popcll(__ballot(b1 < mid)) +
              __popcll(__ballot(b2 < mid)) + __popcll(__ballot(b3 < mid)) +
              __popcll(__ballot(b4 < mid)) + __popcll(__ballot(b5 < mid));
      bool ge = (c >= 32);
      bhi = ge ? mid : bhi;
      blo = ge ? blo : mid;
    }
    unsigned short v32 = (unsigned short)(bhi - 1u);
    d2k = (float)__builtin_bit_cast(__fp16, v32);

    // verify the 32-NN ball (with f16 slack) lies inside the scanned box
    float d32 = sqrtf(d2k) + 1e-2f;
    float mxl = (cxl > 0) ? xg.x - (-4.5f + cxl * CW) : 1e9f;
    float mxh = (cxh < GRIDC - 1) ? (-4.5f + (cxh + 1) * CW) - xg.x : 1e9f;
    float myl = (cyl > 0) ? xg.y - (-4.5f + cyl * CW) : 1e9f;
    float myh = (cyh < GRIDC - 1) ? (-4.5f + (cyh + 1) * CW) - xg.y : 1e9f;
    float margin = fminf(fminf(mxl, mxh), fminf(myl, myh));
    if (d32 <= margin) break;
    r = (3 * r + 1) >> 1;
    if (r > 10) fullA = true;
  }

  const float den = fmaf(2.0f, d2k, 1e-8f);
  const float nc1 = -1.4426950408889634f / den;  // w_scaled = 2^(10 + nc1*d)
  // cut when scaled exponent < -4 (absolute w < 2^-14): d > 14/|nc1| = 9.704*den
  const float dcut = 9.704f * den;

  // ---- phase B: weight sums (windowed or full contiguous) ----
  float sw = 0.f, swx = 0.f, swy = 0.f;
  {
    const int bxl = cellc(xg.x - dcut), bxh = cellc(xg.x + dcut);
    const int byl = cellc(xg.y - dcut), byh = cellc(xg.y + dcut);
    const bool fullB = (byh - byl + 1 > 20);
#define WACC(qp)                                                     \
    {                                                                \
      u32 e = pksub(xihu, qp);                                       \
      float d = __builtin_amdgcn_sqrtf(dot2u(e, e, 0.0f));           \
      float wgt = __builtin_amdgcn_exp2f(fmaf(nc1, d, 10.0f));       \
      h2 ph = __builtin_bit_cast(h2, qp);                            \
      sw += wgt;                                                     \
      swx = fmaf(wgt, (float)ph.x, swx);                             \
      swy = fmaf(wgt, (float)ph.y, swy);                             \
    }
    if (fullB) {
      for (u32 j = (u32)s; j < N_PTS; j += 64u) { u32 qp = spt[j]; WACC(qp); }
    } else {
      u32 acc = 0;
      for (int yy = byl; yy <= byh; ++yy) {
        const int rowb = yy << 6;
        u32 lo = base[rowb + bxl];
        u32 len = base[rowb + bxh + 1] - lo;
        u32 k0 = ((u32)s - acc) & 63u;
        for (u32 k = k0; k < len; k += 64u) { u32 qp = spt[lo + k]; WACC(qp); }
        acc += len;
      }
    }
#undef WACC
  }
#pragma unroll
  for (int m = 1; m < 64; m <<= 1) {
    sw  += __shfl_xor(sw,  m);
    swx += __shfl_xor(swx, m);
    swy += __shfl_xor(swy, m);
  }

  if (s < 2) {
    const float mean = stats[s];
    float inv   = 1.0f / (sw + 1e-8f);               // 2^10 scaling cancels in drift
    float drift = (s == 0 ? swx : swy) * inv - mean;
    float xcv   = (s == 0 ? xg.x : xg.y) - mean;
    uint32_t idx = 2u * (uint32_t)orig + (uint32_t)s;
    float h = fmaf(0.5f, drift - xcv, xcv) + jax_noise(idx);
    h_out[idx] = h;
    hrow[w * 2 + s] = h;
  }
  __syncthreads();
  if (t < 2) {
    double sm = 0.0, sq = 0.0;
#pragma unroll
    for (int k = 0; k < WPB; ++k) {
      double v = (double)hrow[k * 2 + t];
      sm += v; sq += v * v;
    }
    partials[blockIdx.x * 4 + t]     = sm;
    partials[blockIdx.x * 4 + 2 + t] = sq;
  }
}

// ------- K6: every block reduces partials + scales its slice -------
__global__ __launch_bounds__(256) void scalefinal_kernel(const double* __restrict__ partials,
                                                         const float* __restrict__ stats,
                                                         float* __restrict__ h) {
  __shared__ double red[256][4];
  __shared__ float sc[2];
  const int t = threadIdx.x;
  double a0 = 0, a1 = 0, a2 = 0, a3 = 0;
#pragma unroll
  for (int kb = 0; kb < NBLK / 256; ++kb) {
    int b = kb * 256 + t;
    a0 += partials[b * 4 + 0]; a1 += partials[b * 4 + 1];
    a2 += partials[b * 4 + 2]; a3 += partials[b * 4 + 3];
  }
  red[t][0] = a0; red[t][1] = a1; red[t][2] = a2; red[t][3] = a3;
  __syncthreads();
  for (int st = 128; st > 0; st >>= 1) {
    if (t < st) {
      red[t][0] += red[t + st][0]; red[t][1] += red[t + st][1];
      red[t][2] += red[t + st][2]; red[t][3] += red[t + st][3];
    }
    __syncthreads();
  }
  if (t < 2) {
    double n = (double)N_PTS;
    double m = red[0][t] / n;
    double v = (red[0][2 + t] - n * m * m) / (n - 1.0);
    sc[t] = stats[2 + t] / ((float)sqrt(v) + 1e-8f);
  }
  __syncthreads();
  int i = blockIdx.x * 256 + t;
  int d = i & 1;
  h[i] = fmaf(h[i], sc[d], stats[d]);
}

extern "C" void kernel_launch(void* const* d_in, const int* in_sizes, int n_in,
                              void* d_out, int out_size, void* d_ws, size_t ws_size,
                              hipStream_t stream) {
  const float* x = (const float*)d_in[0];
  float* out = (float*)d_out;
  char* W = (char*)d_ws;
  float* stats = (float*)W;                                  // 16 B
  u32* counts = (u32*)(W + 128);                             // 16 KB
  u32* base   = (u32*)(W + 16512);                           // 16.4 KB
  u32* iimg   = (u32*)(W + 33024);                           // 65*65*4 = 16.9 KB
  unsigned short* sidx = (unsigned short*)(W + 50048);       // 16 KB
  u32* tmp_pt = (u32*)(W + 66560);                           // 32 KB
  u32* tmp_ci = (u32*)(W + 99328);                           // 32 KB
  u32* spt    = (u32*)(W + 132096);                          // 32 KB
  double* statpart = (double*)(W + 66560);                   // overlays tmp_pt (dead before place)
  double* partials = (double*)(W + 66560);                   // overlays tmp_pt (dead after rank)

  hipMemsetAsync(counts, 0, NCELL * sizeof(u32), stream);
  count_kernel<<<N_PTS / 256, 256, 0, stream>>>(x, counts, statpart);
  prefix_kernel<<<1, 1024, 0, stream>>>(counts, base, iimg, statpart, stats);
  place_kernel<<<N_PTS / 256, 256, 0, stream>>>(x, counts, tmp_pt, tmp_ci);
  rank_kernel<<<N_PTS / 256, 256, 0, stream>>>(base, tmp_pt, tmp_ci, spt, sidx);
  main_kernel<<<NBLK, TPB, 0, stream>>>(x, stats, base, iimg, spt, sidx, out, partials);
  scalefinal_kernel<<<16384 / 256, 256, 0, stream>>>(partials, stats, out);
}